// Round 2
// baseline (348.678 us; speedup 1.0000x reference)
//
#include <hip/hip_runtime.h>
#include <cstdint>
#include <cstddef>

// ---------------- problem constants ----------------
#define B_    16
#define L_    2048
#define H_    768
#define NE_   64
#define SPAN_ 4
#define NPAIR 2016              // 64*63/2
#define NROWS (B_ * NPAIR)      // 32256

typedef __bf16 bf16_t;
typedef __bf16 bf16x8 __attribute__((ext_vector_type(8)));
typedef float  floatx4 __attribute__((ext_vector_type(4)));

// ---------------- ws layout (bytes, all 256-aligned) ----------------
#define OFF_EMBF   ((size_t)0)
#define OFF_EMBH   ((size_t)3145728)
#define OFF_N      ((size_t)4718592)
#define OFF_COS    ((size_t)7864320)
#define OFF_SIM    ((size_t)8126464)
#define OFF_W1ABT  ((size_t)8255488)
#define OFF_W2T    ((size_t)10614784)
#define OFF_W3T    ((size_t)11401216)
#define OFF_C1     ((size_t)11663360)
#define OFF_H1     ((size_t)17954816)
#define OFF_H2     ((size_t)67500032)
#define OFF_H3     ((size_t)100530176)
#define OFF_FLAG   ((size_t)117045248)
#define OFF_CANON  ((size_t)117045504)
// canon bf16 layout: [0:768) w1row0, [768:1536) b1, [1536:2048) b2,
//                    [2048:2304) b3, [2304:2816) w4, [2816:2818) b4
// total ~117.1 MB

// ---------------- K0: input dtype detection ----------------
// bf16 N(0,1) data: exponent fields ~[110,130]. fp32 data read as ushort:
// even words are random mantissa bits -> uniform exponent -> ~25% "bad".
__global__ __launch_bounds__(256) void detect_kernel(
    const unsigned short* __restrict__ xu, int* __restrict__ flag) {
  __shared__ int tot[4];
  int t = threadIdx.x;
  int bad = 0;
  for (int i = t; i < 4096; i += 256) {
    int e = (xu[i] >> 7) & 0xFF;
    if (e > 133 || (e > 0 && e < 90)) bad++;
  }
  for (int off = 32; off > 0; off >>= 1) bad += __shfl_down(bad, off, 64);
  if ((t & 63) == 0) tot[t >> 6] = bad;
  __syncthreads();
  if (t == 0) flag[0] = ((tot[0] + tot[1] + tot[2] + tot[3]) > 200) ? 1 : 0;
}

__device__ inline bf16_t cvt_elem(const void* p, size_t i, int isf) {
  if (isf) return (bf16_t)(((const float*)p)[i]);
  return ((const bf16_t*)p)[i];
}

// ---------------- K0b: canonical small weights (bf16) ----------------
__global__ __launch_bounds__(256) void conv_small_kernel(
    const void* w1, const void* b1, const void* b2, const void* b3,
    const void* w4, const void* b4, const int* __restrict__ flagp,
    bf16_t* __restrict__ canon) {
  int t = blockIdx.x * 256 + threadIdx.x;
  int isf = flagp[0];
  if (t < 768)       canon[t] = cvt_elem(w1, t, isf);          // w1 row 0 (sim weight)
  else if (t < 1536) canon[t] = cvt_elem(b1, t - 768, isf);
  else if (t < 2048) canon[t] = cvt_elem(b2, t - 1536, isf);
  else if (t < 2304) canon[t] = cvt_elem(b3, t - 2048, isf);
  else if (t < 2816) canon[t] = cvt_elem(w4, t - 2304, isf);
  else if (t < 2818) canon[t] = cvt_elem(b4, t - 2816, isf);
}

// ---------------- K1: span max-pool + norm ----------------
__global__ __launch_bounds__(256) void emb_kernel(
    const void* __restrict__ xv, const int* __restrict__ starts,
    const int* __restrict__ flagp,
    float* __restrict__ embf, bf16_t* __restrict__ embh, float* __restrict__ nmat) {
  int blk = blockIdx.x;
  int b = blk >> 6, e = blk & 63;
  int st = starts[b * NE_ + e];
  size_t off = ((size_t)(b * L_ + st)) * H_;
  int t = threadIdx.x;
  int isf = flagp[0];
  float vals[3];
  float ss = 0.f;
  if (isf) {
    const float* xp = (const float*)xv + off;
#pragma unroll
    for (int c = 0; c < 3; c++) {
      int col = t + c * 256;
      float m = xp[col];
      m = fmaxf(m, xp[H_ + col]);
      m = fmaxf(m, xp[2 * H_ + col]);
      m = fmaxf(m, xp[3 * H_ + col]);
      vals[c] = m;
      ss += m * m;
    }
  } else {
    const bf16_t* xp = (const bf16_t*)xv + off;
#pragma unroll
    for (int c = 0; c < 3; c++) {
      int col = t + c * 256;
      float m = (float)xp[col];
      m = fmaxf(m, (float)xp[H_ + col]);
      m = fmaxf(m, (float)xp[2 * H_ + col]);
      m = fmaxf(m, (float)xp[3 * H_ + col]);
      vals[c] = m;
      ss += m * m;
    }
  }
  __shared__ float red[4];
  __shared__ float inv_s;
  for (int off2 = 32; off2 > 0; off2 >>= 1) ss += __shfl_down(ss, off2, 64);
  if ((t & 63) == 0) red[t >> 6] = ss;
  __syncthreads();
  if (t == 0) {
    float tot = red[0] + red[1] + red[2] + red[3];
    float norm = fmaxf(sqrtf(tot), 1e-8f);
    inv_s = 1.0f / norm;
  }
  __syncthreads();
  float inv = inv_s;
  size_t base = (size_t)blk * H_;
#pragma unroll
  for (int c = 0; c < 3; c++) {
    int col = t + c * 256;
    embf[base + col] = vals[c];
    embh[base + col] = (bf16_t)vals[c];
    nmat[base + col] = vals[c] * inv;
  }
}

// ---------------- K2: cosine matrix ----------------
__global__ __launch_bounds__(256) void cos_kernel(
    const float* __restrict__ nmat, float* __restrict__ cosm) {
  int blk = blockIdx.x;
  int b = blk >> 6, i = blk & 63;
  __shared__ float ni[H_];
  __shared__ float psum[256];
  int t = threadIdx.x;
  for (int c = t; c < H_; c += 256) ni[c] = nmat[(size_t)blk * H_ + c];
  __syncthreads();
  int j = t & 63, chunk = t >> 6;
  const float* nj = nmat + ((size_t)(b * NE_ + j)) * H_;
  float acc = 0.f;
  int h0 = chunk * 192;
  for (int h = h0; h < h0 + 192; h++) acc += ni[h] * nj[h];
  psum[t] = acc;
  __syncthreads();
  if (t < 64) {
    float v = psum[t] + psum[t + 64] + psum[t + 128] + psum[t + 192];
    cosm[(size_t)b * (NE_ * NE_) + i * NE_ + t] = v;
  }
}

// ---------------- K3: per-batch std (ddof=1) + sim ----------------
__global__ __launch_bounds__(256) void sim_kernel(
    const float* __restrict__ cosm, const void* __restrict__ thr_ptr,
    const int* __restrict__ flagp, float* __restrict__ sim) {
  int b = blockIdx.x, t = threadIdx.x;
  const float* cb = cosm + (size_t)b * 4096;
  __shared__ float r0[4], r1[4];
  __shared__ float mean_s, scale_s, thr_s;

  float s = 0.f;
  for (int k = t; k < 4096; k += 256) s += cb[k];
  for (int off = 32; off > 0; off >>= 1) s += __shfl_down(s, off, 64);
  if ((t & 63) == 0) r0[t >> 6] = s;
  __syncthreads();
  if (t == 0) mean_s = (r0[0] + r0[1] + r0[2] + r0[3]) * (1.0f / 4096.0f);
  __syncthreads();
  float mean = mean_s;
  float s2 = 0.f;
  for (int k = t; k < 4096; k += 256) {
    float d = cb[k] - mean;
    s2 += d * d;
  }
  for (int off = 32; off > 0; off >>= 1) s2 += __shfl_down(s2, off, 64);
  if ((t & 63) == 0) r1[t >> 6] = s2;
  __syncthreads();
  if (t == 0) {
    float var = (r1[0] + r1[1] + r1[2] + r1[3]) / 4095.0f;
    float sd = sqrtf(fmaxf(var, 0.f));
    float thv;
    if (flagp[0]) thv = *(const float*)thr_ptr;
    else          thv = (float)(*(const bf16_t*)thr_ptr);
    thr_s = thv;
    scale_s = 1.0f / (sd + 1e-5f);
  }
  __syncthreads();
  float sc = scale_s, th = thr_s;
  for (int p = t; p < NPAIR; p += 256) {
    int i = 0, rem = p;
    while (rem >= 63 - i) { rem -= 63 - i; i++; }
    int j = i + 1 + rem;
    sim[b * NPAIR + p] = (cb[i * 64 + j] - th) * sc;
  }
}

// ---------------- K4: weight transpose [K,N] -> [N,K] (dual dtype in, bf16 out)
__global__ __launch_bounds__(256) void transpose_kernel(
    const void* __restrict__ in, size_t elem_off, bf16_t* __restrict__ out,
    int K, int N, const int* __restrict__ flagp) {
  int idx = blockIdx.x * 256 + threadIdx.x;
  if (idx >= K * N) return;
  int nn = idx / K, kk = idx - nn * K;
  size_t src = elem_off + (size_t)kk * N + nn;
  if (flagp[0]) out[idx] = (bf16_t)(((const float*)in)[src]);
  else          out[idx] = ((const bf16_t*)in)[src];
}

// ---------------- K5: bf16 MFMA GEMM, 128x128 tile, BK=32 (m97 structure)
// A [M,K] rm bf16, Bt [N,K] rm bf16.  MODE 0: C fp32, raw.  MODE 1: C bf16, bias+relu.
template <int MODE>
__global__ __launch_bounds__(256) void gemm_kernel(
    const bf16_t* __restrict__ A, const bf16_t* __restrict__ Bt,
    void* __restrict__ Cv, const bf16_t* __restrict__ bias,
    int M, int N, int K) {
  __shared__ __align__(16) bf16_t Asm[128 * 32];
  __shared__ __align__(16) bf16_t Bsm[128 * 32];
  int bm = blockIdx.x, bn = blockIdx.y;
  int t = threadIdx.x;
  int w = t >> 6, lane = t & 63;
  int quad = lane >> 4, l15 = lane & 15;
  int wm = w >> 1, wn = w & 1;

  floatx4 acc[4][4] = {};

  const char* Abase = (const char*)(A + (size_t)bm * 128 * K);
  const char* Bbase = (const char*)(Bt + (size_t)bn * 128 * K);
  const int rowbytes = K * 2;

  for (int k0 = 0; k0 < K; k0 += 32) {
#pragma unroll
    for (int it = 0; it < 2; it++) {
      int fo = (w * 2 + it) * 1024 + lane * 16;   // byte offset within 8 KB tile
      int row = fo >> 6;                          // 64 B per tile row (32 bf16)
      int colb = fo & 63;
      const char* ga = Abase + (size_t)row * rowbytes + k0 * 2 + colb;
      const char* gb = Bbase + (size_t)row * rowbytes + k0 * 2 + colb;
      __builtin_amdgcn_global_load_lds(
          (__attribute__((address_space(1))) char*)ga,
          (__attribute__((address_space(3))) char*)((char*)Asm + (w * 2 + it) * 1024),
          16, 0, 0);
      __builtin_amdgcn_global_load_lds(
          (__attribute__((address_space(1))) char*)gb,
          (__attribute__((address_space(3))) char*)((char*)Bsm + (w * 2 + it) * 1024),
          16, 0, 0);
    }
    __syncthreads();

    bf16x8 aF[4], bF[4];
#pragma unroll
    for (int tm = 0; tm < 4; tm++) {
      int row = wm * 64 + tm * 16 + l15;
      aF[tm] = *((const bf16x8*)(Asm + row * 32 + quad * 8));
    }
#pragma unroll
    for (int tn = 0; tn < 4; tn++) {
      int row = wn * 64 + tn * 16 + l15;
      bF[tn] = *((const bf16x8*)(Bsm + row * 32 + quad * 8));
    }
#pragma unroll
    for (int tm = 0; tm < 4; tm++)
#pragma unroll
      for (int tn = 0; tn < 4; tn++)
        acc[tm][tn] = __builtin_amdgcn_mfma_f32_16x16x32_bf16(aF[tm], bF[tn], acc[tm][tn], 0, 0, 0);
    __syncthreads();
  }

  // C/D layout: row = quad*4 + reg, col = l15 (m89/m91-verified)
#pragma unroll
  for (int tm = 0; tm < 4; tm++) {
    int grow0 = bm * 128 + wm * 64 + tm * 16 + quad * 4;
#pragma unroll
    for (int tn = 0; tn < 4; tn++) {
      int gcol = bn * 128 + wn * 64 + tn * 16 + l15;
#pragma unroll
      for (int r = 0; r < 4; r++) {
        size_t o = (size_t)(grow0 + r) * N + gcol;
        float v = acc[tm][tn][r];
        if (MODE == 0) {
          ((float*)Cv)[o] = v;
        } else {
          v += (float)bias[gcol];
          v = fmaxf(v, 0.f);
          ((bf16_t*)Cv)[o] = (bf16_t)v;
        }
      }
    }
  }
}

// ---------------- K6: layer-1 assembly ----------------
// h1[r,c] = relu(C1[i-row, c] + C1[j-row, 768+c] + sim*w1r0[c] + b1[c])
__global__ __launch_bounds__(256) void assemble_kernel(
    const float* __restrict__ C1, const float* __restrict__ sim,
    const bf16_t* __restrict__ canon, bf16_t* __restrict__ h1) {
  int r = blockIdx.x;
  int b = r / NPAIR, p = r - b * NPAIR;
  int i = 0, rem = p;
  while (rem >= 63 - i) { rem -= 63 - i; i++; }
  int j = i + 1 + rem;
  float s = sim[b * NPAIR + p];
  const float* Ai = C1 + (size_t)(b * NE_ + i) * 1536;
  const float* Bj = C1 + (size_t)(b * NE_ + j) * 1536 + 768;
  const bf16_t* w1r0 = canon;
  const bf16_t* b1c  = canon + 768;
  size_t ob = (size_t)r * H_;
  int t = threadIdx.x;
#pragma unroll
  for (int c0 = 0; c0 < 3; c0++) {
    int c = t + c0 * 256;
    float v = Ai[c] + Bj[c] + s * (float)w1r0[c] + (float)b1c[c];
    h1[ob + c] = (bf16_t)fmaxf(v, 0.f);
  }
}

// ---------------- K7: final 256 -> 2 layer, one wave per row ----------------
__global__ __launch_bounds__(256) void final_kernel(
    const bf16_t* __restrict__ h3, const bf16_t* __restrict__ canon,
    const int* __restrict__ flagp, void* __restrict__ out) {
  int wid = threadIdx.x >> 6, lane = threadIdx.x & 63;
  int r = blockIdx.x * 4 + wid;
  const bf16_t* hp = h3 + (size_t)r * 256 + lane * 4;
  const bf16_t* wp = canon + 2304 + lane * 8;   // w4 canonical [k*2+c]
  float a0 = 0.f, a1 = 0.f;
#pragma unroll
  for (int u = 0; u < 4; u++) {
    float hv = (float)hp[u];
    a0 += hv * (float)wp[u * 2];
    a1 += hv * (float)wp[u * 2 + 1];
  }
  for (int off = 32; off > 0; off >>= 1) {
    a0 += __shfl_down(a0, off, 64);
    a1 += __shfl_down(a1, off, 64);
  }
  if (lane == 0) {
    float o0 = a0 + (float)canon[2816];
    float o1 = a1 + (float)canon[2817];
    if (flagp[0]) {
      ((float*)out)[(size_t)r * 2]     = o0;
      ((float*)out)[(size_t)r * 2 + 1] = o1;
    } else {
      ((bf16_t*)out)[(size_t)r * 2]     = (bf16_t)o0;
      ((bf16_t*)out)[(size_t)r * 2 + 1] = (bf16_t)o1;
    }
  }
}

// ---------------- launch ----------------
extern "C" void kernel_launch(void* const* d_in, const int* in_sizes, int n_in,
                              void* d_out, int out_size, void* d_ws, size_t ws_size,
                              hipStream_t stream) {
  const void* x      = d_in[0];
  const void* thr    = d_in[1];
  const void* w1     = d_in[2];
  const void* b1     = d_in[3];
  const void* w2     = d_in[4];
  const void* b2     = d_in[5];
  const void* w3     = d_in[6];
  const void* b3     = d_in[7];
  const void* w4     = d_in[8];
  const void* b4     = d_in[9];
  const int*  starts = (const int*)d_in[10];

  char* ws = (char*)d_ws;
  float*  embf  = (float*)(ws + OFF_EMBF);
  bf16_t* embh  = (bf16_t*)(ws + OFF_EMBH);
  float*  nmat  = (float*)(ws + OFF_N);
  float*  cosm  = (float*)(ws + OFF_COS);
  float*  simv  = (float*)(ws + OFF_SIM);
  bf16_t* w1abT = (bf16_t*)(ws + OFF_W1ABT);
  bf16_t* w2T   = (bf16_t*)(ws + OFF_W2T);
  bf16_t* w3T   = (bf16_t*)(ws + OFF_W3T);
  float*  C1    = (float*)(ws + OFF_C1);
  bf16_t* h1    = (bf16_t*)(ws + OFF_H1);
  bf16_t* h2    = (bf16_t*)(ws + OFF_H2);
  bf16_t* h3    = (bf16_t*)(ws + OFF_H3);
  int*    flag  = (int*)(ws + OFF_FLAG);
  bf16_t* canon = (bf16_t*)(ws + OFF_CANON);

  detect_kernel<<<1, 256, 0, stream>>>((const unsigned short*)x, flag);
  conv_small_kernel<<<12, 256, 0, stream>>>(w1, b1, b2, b3, w4, b4, flag, canon);

  // weight transposes into [N,K] bf16: W1a rows 1..768, W1b rows 769..1536 of w1
  transpose_kernel<<<(768 * 768 + 255) / 256, 256, 0, stream>>>(w1, (size_t)768,       w1abT,             768, 768, flag);
  transpose_kernel<<<(768 * 768 + 255) / 256, 256, 0, stream>>>(w1, (size_t)769 * 768, w1abT + 768 * 768, 768, 768, flag);
  transpose_kernel<<<(768 * 512 + 255) / 256, 256, 0, stream>>>(w2, (size_t)0, w2T, 768, 512, flag);
  transpose_kernel<<<(512 * 256 + 255) / 256, 256, 0, stream>>>(w3, (size_t)0, w3T, 512, 256, flag);

  emb_kernel<<<B_ * NE_, 256, 0, stream>>>(x, starts, flag, embf, embh, nmat);
  cos_kernel<<<B_ * NE_, 256, 0, stream>>>(nmat, cosm);
  sim_kernel<<<B_, 256, 0, stream>>>(cosm, thr, flag, simv);

  // C1 = emb @ [W1a | W1b] : [1024,768] x [768,1536] -> fp32
  {
    dim3 g(1024 / 128, 1536 / 128);
    gemm_kernel<0><<<g, 256, 0, stream>>>(embh, w1abT, (void*)C1, nullptr, 1024, 1536, 768);
  }
  assemble_kernel<<<NROWS, 256, 0, stream>>>(C1, simv, canon, h1);
  // h2 = relu(h1 @ w2 + b2) : [32256,768] x [768,512]
  {
    dim3 g(NROWS / 128, 512 / 128);
    gemm_kernel<1><<<g, 256, 0, stream>>>(h1, w2T, (void*)h2, canon + 1536, NROWS, 512, 768);
  }
  // h3 = relu(h2 @ w3 + b3) : [32256,512] x [512,256]
  {
    dim3 g(NROWS / 128, 256 / 128);
    gemm_kernel<1><<<g, 256, 0, stream>>>(h2, w3T, (void*)h3, canon + 2048, NROWS, 256, 512);
  }
  final_kernel<<<NROWS / 4, 256, 0, stream>>>(h3, canon, flag, d_out);
}